// Round 3
// baseline (424.193 us; speedup 1.0000x reference)
//
#include <hip/hip_runtime.h>
#include <hip/hip_bf16.h>

typedef __attribute__((ext_vector_type(8))) short bf16x8;
typedef __attribute__((ext_vector_type(4))) float f32x4;
typedef __attribute__((ext_vector_type(8))) unsigned short u16x8;
typedef __attribute__((ext_vector_type(4))) unsigned short u16x4;

#define BN_EPS 1e-5f

__device__ __forceinline__ unsigned short f2bf(float f) {
  unsigned int u = __float_as_uint(f);
  unsigned int r = u + 0x7FFFu + ((u >> 16) & 1u);
  return (unsigned short)(r >> 16);
}
__device__ __forceinline__ float bf2f(unsigned short u) {
  union { float f; unsigned int i; } v; v.i = ((unsigned int)u) << 16; return v.f;
}

// ---------------------------------------------------------------------------
// K0: fold BN params -> bias1[256] fp32, W2f[9*256] fp32 (scale folded), bias2[9]
__global__ __launch_bounds__(256) void params_kernel(
    const float* __restrict__ g1, const float* __restrict__ b1,
    const float* __restrict__ m1, const float* __restrict__ v1,
    const float* __restrict__ W2, const float* __restrict__ g2,
    const float* __restrict__ b2, const float* __restrict__ m2,
    const float* __restrict__ v2,
    float* __restrict__ bias1, float* __restrict__ W2f, float* __restrict__ bias2)
{
  int t = threadIdx.x;
  {
    float s = g1[t] * rsqrtf(v1[t] + BN_EPS);
    bias1[t] = b1[t] - m1[t] * s;
  }
  for (int i = t; i < 2304; i += 256) {
    int j = i >> 8;
    float s2 = g2[j] * rsqrtf(v2[j] + BN_EPS);
    W2f[i] = W2[i] * s2;
  }
  if (t < 9) {
    float s2 = g2[t] * rsqrtf(v2[t] + BN_EPS);
    bias2[t] = b2[t] - m2[t] * s2;
  }
}

// ---------------------------------------------------------------------------
// K1: fold scale1 into W1, quantize to bf16, transpose to Bt[o][tap*256 + i]
__global__ __launch_bounds__(256) void fold_w1_kernel(
    const float* __restrict__ W1, const float* __restrict__ g1,
    const float* __restrict__ v1, unsigned short* __restrict__ Bt)
{
  int idx = blockIdx.x * 256 + threadIdx.x;   // 0 .. 589823
  int o = idx / 2304;
  int k = idx - o * 2304;
  int tap = k >> 8;
  int i = k & 255;
  float s = g1[o] * rsqrtf(v1[o] + BN_EPS);
  Bt[idx] = f2bf(W1[o * 2304 + i * 9 + tap] * s);
}

// ---------------------------------------------------------------------------
// K2: y (fp32 NCHW) -> zero-padded bf16 NHWC  yTp[n][hh][ww][c], hh,ww in [0,66)
// border pre-zeroed by memset. One block per (n,h) row.
__global__ __launch_bounds__(256) void transpose_pad_kernel(
    const float* __restrict__ y, unsigned short* __restrict__ yTp)
{
  __shared__ unsigned short T[64][68];
  int t = threadIdx.x;
  int nb = blockIdx.x; int n = nb >> 6, h = nb & 63;
  int w4 = (t & 15) * 4;
  int cl = t >> 4;           // 0..15
  int cw = t & 63;           // write-phase c_local
  int wi = t >> 6;           // 0..3
  for (int cb = 0; cb < 4; ++cb) {
    __syncthreads();
    #pragma unroll
    for (int r = 0; r < 4; ++r) {
      int c = cb * 64 + cl + r * 16;
      const float* src = y + ((((size_t)n * 256 + c) * 64 + h) << 6) + w4;
      float4 v = *(const float4*)src;
      u16x4 pv = { f2bf(v.x), f2bf(v.y), f2bf(v.z), f2bf(v.w) };
      *(u16x4*)&T[cl + r * 16][w4] = pv;
    }
    __syncthreads();
    size_t obase = ((((size_t)n * 66 + (h + 1)) * 66) + 1) * 256 + cb * 64 + cw;
    #pragma unroll
    for (int r = 0; r < 16; ++r) {
      int w = wi + r * 4;
      yTp[obase + (size_t)w * 256] = T[cw][w];
    }
  }
}

// ---------------------------------------------------------------------------
// K3: conv3x3 as implicit GEMM (bf16 MFMA, fp32 accum). Block = (n,h):
// 64 pixels x 256 c_out, K=2304. 4 waves, each 64x64 via 4x4 of 16x16x32.
__global__ __launch_bounds__(256, 2) void conv3x3_mfma_kernel(
    const unsigned short* __restrict__ yTp, const unsigned short* __restrict__ Bt,
    const float* __restrict__ bias1, const float* __restrict__ a1p,
    unsigned short* __restrict__ hT)
{
  __shared__ unsigned short Als[64 * 40];    // A tile [64 m][32 k], stride 40
  __shared__ unsigned short Bls[256 * 40];   // B tile [256 n][32 k], stride 40
  int tid = threadIdx.x;
  int nb = blockIdx.x;
  int n = nb >> 6, h = nb & 63;
  int am = tid >> 2;               // A-stage row (pixel w), 0..63
  int aseg = (tid & 3) * 8;        // A-stage k offset
  int l = tid & 63, wv = tid >> 6;
  int quad = l >> 4, lr = l & 15;

  f32x4 acc[4][4];
  #pragma unroll
  for (int im = 0; im < 4; ++im)
    #pragma unroll
    for (int in_ = 0; in_ < 4; ++in_)
      acc[im][in_] = (f32x4){0.f, 0.f, 0.f, 0.f};

  const size_t nbase = (size_t)n * 66 * 66;

  for (int it = 0; it < 72; ++it) {
    int tap = it >> 3;
    int ci0 = (it & 7) << 5;
    int ti = tap / 3;
    int tj = tap - ti * 3;
    // A: yTp[n][h+ti][am+tj][ci0 + aseg .. +8]
    const unsigned short* ga =
        yTp + ((nbase + (size_t)(h + ti) * 66 + (am + tj)) << 8) + ci0 + aseg;
    u16x8 av = *(const u16x8*)ga;
    // B: Bt[tid][tap*256 + ci0 .. +32]
    const unsigned short* gb = Bt + (size_t)tid * 2304 + (tap << 8) + ci0;
    u16x8 bv0 = *(const u16x8*)gb;
    u16x8 bv1 = *(const u16x8*)(gb + 8);
    u16x8 bv2 = *(const u16x8*)(gb + 16);
    u16x8 bv3 = *(const u16x8*)(gb + 24);
    __syncthreads();
    *(u16x8*)&Als[am * 40 + aseg] = av;
    *(u16x8*)&Bls[tid * 40 + 0] = bv0;
    *(u16x8*)&Bls[tid * 40 + 8] = bv1;
    *(u16x8*)&Bls[tid * 40 + 16] = bv2;
    *(u16x8*)&Bls[tid * 40 + 24] = bv3;
    __syncthreads();
    bf16x8 af[4], bfr[4];
    #pragma unroll
    for (int im = 0; im < 4; ++im)
      af[im] = *(const bf16x8*)&Als[(im * 16 + lr) * 40 + quad * 8];
    #pragma unroll
    for (int in_ = 0; in_ < 4; ++in_)
      bfr[in_] = *(const bf16x8*)&Bls[(wv * 64 + in_ * 16 + lr) * 40 + quad * 8];
    #pragma unroll
    for (int im = 0; im < 4; ++im)
      #pragma unroll
      for (int in_ = 0; in_ < 4; ++in_)
        acc[im][in_] = __builtin_amdgcn_mfma_f32_16x16x32_bf16(
            af[im], bfr[in_], acc[im][in_], 0, 0, 0);
  }

  float a1 = a1p[0];
  size_t pbase = (size_t)nb * 64;
  #pragma unroll
  for (int in_ = 0; in_ < 4; ++in_) {
    int c = wv * 64 + in_ * 16 + lr;
    float bs = bias1[c];
    #pragma unroll
    for (int im = 0; im < 4; ++im) {
      int m0 = im * 16 + quad * 4;
      #pragma unroll
      for (int r = 0; r < 4; ++r) {
        float v = acc[im][in_][r] + bs;
        v = (v >= 0.f) ? v : a1 * v;
        hT[(pbase + m0 + r) * 256 + c] = f2bf(v);
      }
    }
  }
}

// ---------------------------------------------------------------------------
// K4: 1x1 conv C->9 + BN + PReLU. kernP planar fp32 [9][65536].
__global__ __launch_bounds__(256) void conv1x1_kernel(
    const unsigned short* __restrict__ hT, const float* __restrict__ W2f,
    const float* __restrict__ bias2, const float* __restrict__ a2p,
    float* __restrict__ kernP)
{
  __shared__ float w2s[2304];
  int t = threadIdx.x;
  for (int i = t; i < 2304; i += 256) w2s[i] = W2f[i];
  __syncthreads();
  int p = blockIdx.x * 256 + t;
  const unsigned short* hp = hT + (size_t)p * 256;
  float acc[9];
  #pragma unroll
  for (int j = 0; j < 9; ++j) acc[j] = 0.f;
  for (int c0 = 0; c0 < 256; c0 += 8) {
    u16x8 hv = *(const u16x8*)(hp + c0);
    float hf[8];
    #pragma unroll
    for (int i = 0; i < 8; ++i) hf[i] = bf2f(hv[i]);
    #pragma unroll
    for (int j = 0; j < 9; ++j)
      #pragma unroll
      for (int i = 0; i < 8; ++i)
        acc[j] = fmaf(hf[i], w2s[j * 256 + c0 + i], acc[j]);
  }
  float a2 = a2p[0];
  #pragma unroll
  for (int j = 0; j < 9; ++j) {
    float v = acc[j] + bias2[j];
    v = (v >= 0.f) ? v : a2 * v;
    kernP[j * 65536 + p] = v;
  }
}

// ---------------------------------------------------------------------------
// K5: scrambled unfold-reshape apply (faithful to reference's row-major
// reshape [N,C,9,H,W] -> [N,H,W,C,9]).
// out[n][c'][h'][w'] = sum_{k'=0..8} P(n, lin) * kern[k'][n,h',w']
//   lin = h'*147456 + w'*2304 + c'*9 + k'
//   c   = 4h' + (w'>>4)                       (never carries)
//   r   = (w'&15)*2304 + c'*9 + k'            (< 36864)
//   k = r>>12; h = (r&4095)>>6; w = r&63; (i,j) = (k/3, k%3)
//   P = x[n, c, h+i-1, w+j-1]  (zero padded)
// Block = (n, h', g=w'>>4): stages exactly one x-plane (bijection) in LDS.
__global__ __launch_bounds__(256) void apply_dyn_kernel(
    const float* __restrict__ x, const float* __restrict__ kernP,
    float* __restrict__ out)
{
  __shared__ float xs[64 * 65];   // x[n][c] plane, stride 65 (bank spread)
  __shared__ float ks[9][16];
  int t = threadIdx.x;
  int b = blockIdx.x;             // ((n*64 + h')*4 + g)
  int g = b & 3;
  int nh = b >> 2;
  int n = nh >> 6, hp = nh & 63;
  int c = 4 * hp + g;

  const float* xplane = x + (((size_t)n * 256 + c) << 12);
  for (int i = t; i < 1024; i += 256) {
    float4 v = *(const float4*)(xplane + i * 4);
    int row = i >> 4;
    int col = (i * 4) & 63;
    float* d = &xs[row * 65 + col];
    d[0] = v.x; d[1] = v.y; d[2] = v.z; d[3] = v.w;
  }
  int pbase = n * 4096 + hp * 64 + g * 16;
  for (int i = t; i < 144; i += 256)
    ks[i / 16][i & 15] = kernP[(i / 16) * 65536 + pbase + (i & 15)];
  __syncthreads();

  int s = t & 15;                 // w' & 15
  int crow = t >> 4;              // c' low part
  float ksr[9];
  #pragma unroll
  for (int k2 = 0; k2 < 9; ++k2) ksr[k2] = ks[k2][s];

  int r0base = s * 2304 + crow * 9;
  #pragma unroll 4
  for (int jj = 0; jj < 16; ++jj) {
    int cp = crow + 16 * jj;      // c'
    int r0 = r0base + 144 * jj;
    float acc = 0.f;
    #pragma unroll
    for (int k2 = 0; k2 < 9; ++k2) {
      int r = r0 + k2;
      int k = r >> 12;
      int rem = r & 4095;
      int h = rem >> 6;
      int w = rem & 63;
      int ti = k / 3;
      int tj = k - 3 * ti;
      int hh = h + ti - 1;
      int ww = w + tj - 1;
      float xv = 0.f;
      if ((unsigned)hh < 64u && (unsigned)ww < 64u) xv = xs[hh * 65 + ww];
      acc = fmaf(xv, ksr[k2], acc);
    }
    out[(((size_t)n * 256 + cp) << 12) + (hp << 6) + g * 16 + s] = acc;
  }
}

// ---------------------------------------------------------------------------
extern "C" void kernel_launch(void* const* d_in, const int* in_sizes, int n_in,
                              void* d_out, int out_size, void* d_ws, size_t ws_size,
                              hipStream_t stream) {
  const float* x  = (const float*)d_in[0];
  const float* y  = (const float*)d_in[1];
  const float* W1 = (const float*)d_in[2];
  const float* g1 = (const float*)d_in[3];
  const float* b1 = (const float*)d_in[4];
  const float* m1 = (const float*)d_in[5];
  const float* v1 = (const float*)d_in[6];
  const float* a1 = (const float*)d_in[7];
  const float* W2 = (const float*)d_in[8];
  const float* g2 = (const float*)d_in[9];
  const float* b2 = (const float*)d_in[10];
  const float* m2 = (const float*)d_in[11];
  const float* v2 = (const float*)d_in[12];
  const float* a2 = (const float*)d_in[13];
  float* out = (float*)d_out;

  char* ws = (char*)d_ws;
  size_t off = 0;
  const size_t yTp_bytes = (size_t)16 * 66 * 66 * 256 * 2;   // 35,684,352
  unsigned short* yTp = (unsigned short*)(ws + off); off += yTp_bytes;
  unsigned short* Bt  = (unsigned short*)(ws + off); off += (size_t)589824 * 2;
  unsigned short* hT  = (unsigned short*)(ws + off); off += (size_t)16777216 * 2;
  float* kernP = (float*)(ws + off); off += (size_t)589824 * 4;
  float* bias1 = (float*)(ws + off); off += 1024;
  float* W2f   = (float*)(ws + off); off += 9216;
  float* bias2 = (float*)(ws + off); off += 64;

  hipMemsetAsync(yTp, 0, yTp_bytes, stream);
  params_kernel<<<1, 256, 0, stream>>>(g1, b1, m1, v1, W2, g2, b2, m2, v2,
                                       bias1, W2f, bias2);
  fold_w1_kernel<<<2304, 256, 0, stream>>>(W1, g1, v1, Bt);
  transpose_pad_kernel<<<1024, 256, 0, stream>>>(y, yTp);
  conv3x3_mfma_kernel<<<1024, 256, 0, stream>>>(yTp, Bt, bias1, a1, hT);
  conv1x1_kernel<<<256, 256, 0, stream>>>(hT, W2f, bias2, a2, kernP);
  apply_dyn_kernel<<<4096, 256, 0, stream>>>(x, kernP, out);
}